// Round 7
// baseline (708.849 us; speedup 1.0000x reference)
//
#include <hip/hip_runtime.h>

#define T_TOK 2048
#define HDIM  2048
#define FDIM  4096
#define NEXP  8

typedef float f32x4 __attribute__((ext_vector_type(4)));
typedef float fvec4 __attribute__((ext_vector_type(4)));
typedef float fvec2 __attribute__((ext_vector_type(2)));
typedef short s16x4 __attribute__((ext_vector_type(4)));
typedef short s16x8 __attribute__((ext_vector_type(8)));
typedef unsigned uint2v __attribute__((ext_vector_type(2)));

__device__ __forceinline__ short f2bf(float f) {
  union { float f; unsigned u; } c; c.f = f;
  unsigned r = c.u + 0x7FFFu + ((c.u >> 16) & 1u);
  return (short)(r >> 16);
}
__device__ __forceinline__ float bf2f(short h) {
  union { float f; unsigned u; } c; c.u = ((unsigned)(unsigned short)h) << 16;
  return c.f;
}
__device__ __forceinline__ unsigned cvtpk(float lo, float hi) {
  unsigned r;
  asm("v_cvt_pk_bf16_f32 %0, %1, %2" : "=v"(r) : "v"(lo), "v"(hi));
  return r;
}

#define GLL16(gsrc, ldst) \
  __builtin_amdgcn_global_load_lds((const __attribute__((address_space(1))) void*)(gsrc), \
                                   (__attribute__((address_space(3))) void*)(ldst), 16, 0, 0)

// ---------------- weight convert + transpose: W fp32 [K,N] -> WT bf16 [N,K] ----
__global__ __launch_bounds__(256) void tconv_kernel(
    const float* __restrict__ W, short* __restrict__ WT, int K, int N)
{
  __shared__ float tile[64][65];
  int n0 = blockIdx.x * 64, k0 = blockIdx.y * 64;
  int t = threadIdx.x;
  int tc = t & 15, tr = t >> 4;
  #pragma unroll
  for (int i = 0; i < 4; i++) {
    int k = tr + i * 16;
    fvec4 v = *(const fvec4*)(W + (size_t)(k0 + k) * N + n0 + tc * 4);
    tile[k][tc * 4 + 0] = v.x; tile[k][tc * 4 + 1] = v.y;
    tile[k][tc * 4 + 2] = v.z; tile[k][tc * 4 + 3] = v.w;
  }
  __syncthreads();
  int n = t >> 2, ks = (t & 3) * 16;
  s16x8 o0, o1;
  #pragma unroll
  for (int j = 0; j < 8; j++) {
    o0[j] = f2bf(tile[ks + j][n]);
    o1[j] = f2bf(tile[ks + 8 + j][n]);
  }
  *(s16x8*)(WT + (size_t)(n0 + n) * K + k0 + ks) = o0;
  *(s16x8*)(WT + (size_t)(n0 + n) * K + k0 + ks + 8) = o1;
}

// ---------------- router: logits + top1 + sigmoid score ----------------
__global__ __launch_bounds__(256) void router_kernel(
    const float* __restrict__ h, const float* __restrict__ rw,
    float* __restrict__ logits, int* __restrict__ eid, float* __restrict__ score)
{
  int tok  = blockIdx.x * 4 + (threadIdx.x >> 6);
  int lane = threadIdx.x & 63;
  float a[8] = {0.f,0.f,0.f,0.f,0.f,0.f,0.f,0.f};
  const float* hp = h + (size_t)tok * HDIM;
  for (int i = lane; i < HDIM; i += 64) {
    float hv = hp[i];
    const fvec4* wp = (const fvec4*)(rw + (size_t)i * NEXP);
    fvec4 w0 = wp[0], w1 = wp[1];
    a[0] += hv * w0.x; a[1] += hv * w0.y; a[2] += hv * w0.z; a[3] += hv * w0.w;
    a[4] += hv * w1.x; a[5] += hv * w1.y; a[6] += hv * w1.z; a[7] += hv * w1.w;
  }
  #pragma unroll
  for (int e = 0; e < 8; e++) {
    #pragma unroll
    for (int off = 32; off; off >>= 1)
      a[e] += __shfl_xor(a[e], off, 64);
  }
  if (lane == 0) {
    float best = a[0]; int bi = 0;
    #pragma unroll
    for (int e = 1; e < 8; e++) if (a[e] > best) { best = a[e]; bi = e; }
    #pragma unroll
    for (int e = 0; e < 8; e++) logits[(size_t)tok * NEXP + e] = a[e];
    eid[tok] = bi;
    score[tok] = 1.0f / (1.0f + __expf(-best));
  }
}

// ---------------- stable counting sort of tokens by expert ----------------
__global__ __launch_bounds__(512) void sort_kernel(
    const int* __restrict__ eid, int* __restrict__ perm, int* __restrict__ ofs)
{
  __shared__ int s_cnt[8];
  __shared__ int s_off[9];
  int w = threadIdx.x >> 6, lane = threadIdx.x & 63;
  int cnt = 0;
  for (int b = 0; b < T_TOK; b += 64) {
    int id = eid[b + lane];
    unsigned long long m = __ballot(id == w);
    cnt += __popcll(m);
  }
  if (lane == 0) s_cnt[w] = cnt;
  __syncthreads();
  if (threadIdx.x == 0) {
    int o = 0;
    for (int e = 0; e < 8; e++) { s_off[e] = o; o += s_cnt[e]; }
    s_off[8] = o;
    for (int e = 0; e < 9; e++) ofs[e] = s_off[e];
  }
  __syncthreads();
  int pos = s_off[w];
  for (int b = 0; b < T_TOK; b += 64) {
    int tokidx = b + lane;
    int id = eid[tokidx];
    unsigned long long m = __ballot(id == w);
    if (id == w) {
      int p = pos + __popcll(m & ((1ull << lane) - 1ull));
      perm[p] = tokidx;
    }
    pos += __popcll(m);
  }
}

// ---------------- build bf16 h and permuted+scaled x ----------------
__global__ __launch_bounds__(256) void build_kernel(
    const float* __restrict__ h, const float* __restrict__ score,
    const int* __restrict__ perm, short* __restrict__ hb, short* __restrict__ xp)
{
  int row = blockIdx.x;
  int t = threadIdx.x;
  const fvec4* s1 = (const fvec4*)(h + (size_t)row * HDIM);
  for (int j = t; j < HDIM/4; j += 256) {
    fvec4 v = s1[j];
    s16x4 o = { f2bf(v.x), f2bf(v.y), f2bf(v.z), f2bf(v.w) };
    *(s16x4*)(hb + (size_t)row * HDIM + j*4) = o;
  }
  int tok = perm[row];
  float s = score[tok];
  const fvec4* s2 = (const fvec4*)(h + (size_t)tok * HDIM);
  for (int j = t; j < HDIM/4; j += 256) {
    fvec4 v = s2[j];
    s16x4 o = { f2bf(v.x*s), f2bf(v.y*s), f2bf(v.z*s), f2bf(v.w*s) };
    *(s16x4*)(xp + (size_t)row * HDIM + j*4) = o;
  }
}

// ---------------- unified MoE GEMM, 2-phase double-buffered ----------------
// MODE 0: fused gate-up 2-pass (B16 only); epi silu(g)*u -> bf16
// MODE 1: plain fp32 store
// MODE 2: fp32 scatter-accumulate via perm rows
// MODE 3: plain bf16 store (raw)
// MODE 4: epi: g=graw[addr]; silu(g)*acc -> bf16 store
// B16=false: B fp32 [K,N] row-major, reg-staged + cvt_pk.
// B16=true : B bf16 [N,K] row-major, global_load_lds staged.
template<int MODE, bool B16, int BM_, int BN_, int BK_, int WM, int WN, int OCC>
__global__ __launch_bounds__(256, OCC) void moe_gemm(
    const short* __restrict__ A, int lda,
    const void* __restrict__ B0v, const void* __restrict__ B1v,
    long long bstride, int ldb,
    void* __restrict__ Cv, int ldc,
    const int* __restrict__ gofs, int mt_per_g, int K,
    const int* __restrict__ perm, const short* __restrict__ graw)
{
  constexpr int MROW = BM_ / WM;
  constexpr int NCOL = BN_ / WN;
  constexpr int MREP = MROW / 16;
  constexpr int NREP = NCOL / 16;
  constexpr int CHM  = BK_ / 8 - 1;      // swizzle slot mask
  constexpr int LPR  = BK_ / 8;          // lanes per A row in a gll
  constexpr int RPG  = 512 / BK_;        // rows per gll (1024B)
  constexpr int GPW  = BM_ / RPG / 4;    // A glls per wave
  constexpr int BGW  = B16 ? (BN_ / RPG / 4) : 1;  // B glls per wave (B16)
  constexpr int BKP_ = B16 ? BK_ : (BK_ + 4);
  constexpr int UPT  = B16 ? 1 : (BN_ * BK_ / 8 / 256);  // fp32 stage units/thread

  __shared__ short sA[2][BM_ * BK_];
  __shared__ short sB[2][BN_ * BKP_];

  int g  = blockIdx.y / mt_per_g;
  int mt = blockIdx.y % mt_per_g;
  int r0 = 0, r1 = T_TOK;
  if (gofs) { r0 = gofs[g]; r1 = gofs[g+1]; }
  int row0 = r0 + mt * BM_;
  if (row0 >= r1) return;
  int rows = r1 - row0; if (rows > BM_) rows = BM_;
  int n0 = blockIdx.x * BN_;

  const float* Bg32 = nullptr; const float* Bu32 = nullptr;
  const short* Bg16 = nullptr; const short* Bu16 = nullptr;
  if constexpr (B16) {
    Bg16 = (const short*)B0v + (size_t)g * (size_t)bstride;
    if (MODE == 0) Bu16 = (const short*)B1v + (size_t)g * (size_t)bstride;
  } else {
    Bg32 = (const float*)B0v + (size_t)g * (size_t)bstride;
  }

  int tid = threadIdx.x;
  int lane = tid & 63, w = tid >> 6;
  int wr = (w / WN) * MROW;
  int wc = (w % WN) * NCOL;
  int l16 = lane & 15, lh = lane >> 4;

  // gll A/B lane mapping
  int arow_in = lane / LPR;
  int akoff   = (((lane % LPR) ^ (arow_in & CHM)) << 3);  // swizzled k offset (shorts)
  const short* aBase[GPW];
  #pragma unroll
  for (int i = 0; i < GPW; i++) {
    int row = (w * GPW + i) * RPG + arow_in;
    int growc = row0 + row; if (growc > T_TOK - 1) growc = T_TOK - 1;
    aBase[i] = A + (size_t)growc * lda + akoff;
  }

  const int KT = K / BK_;
  const int NTILES = (MODE == 0) ? 2 * KT : KT;

  f32x4 zero4 = {0.f, 0.f, 0.f, 0.f};
  f32x4 acc[MREP][NREP];
  #pragma unroll
  for (int m = 0; m < MREP; m++)
    #pragma unroll
    for (int n = 0; n < NREP; n++) acc[m][n] = zero4;
  s16x4 sgate[MODE == 0 ? MREP : 1][MODE == 0 ? NREP : 1];
  fvec2 Breg[UPT][4];

  auto stage_issue = [&](int tt, int bb) {
    int k0 = (tt & (KT - 1)) * BK_;
    if constexpr (B16) {
      const short* BTp = (MODE == 0 && tt >= KT) ? Bu16 : Bg16;
      #pragma unroll
      for (int i = 0; i < BGW; i++) {
        int rbase = (w * BGW + i) * RPG;
        const short* src = BTp + (size_t)(n0 + rbase + arow_in) * ldb + k0 + akoff;
        GLL16(src, &sB[bb][rbase * BK_]);
      }
    } else {
      const float* Bp = Bg32;
      #pragma unroll
      for (int u = 0; u < UPT; u++) {
        int unit = tid + u * 256;
        int c2 = unit % (BN_ / 2);
        int kq = unit / (BN_ / 2);
        const float* bp = Bp + (size_t)(k0 + kq * 4) * ldb + n0 + c2 * 2;
        #pragma unroll
        for (int r = 0; r < 4; r++)
          Breg[u][r] = *(const fvec2*)(bp + (size_t)r * ldb);
      }
    }
    #pragma unroll
    for (int i = 0; i < GPW; i++)
      GLL16(aBase[i] + k0, &sA[bb][(w * GPW + i) * RPG * BK_]);
  };
  auto stage_write = [&](int bb) {
    if constexpr (!B16) {
      #pragma unroll
      for (int u = 0; u < UPT; u++) {
        int unit = tid + u * 256;
        int c2 = unit % (BN_ / 2);
        int kq = unit / (BN_ / 2);
        uint2v lo, hi;
        lo.x = cvtpk(Breg[u][0].x, Breg[u][1].x);
        lo.y = cvtpk(Breg[u][2].x, Breg[u][3].x);
        hi.x = cvtpk(Breg[u][0].y, Breg[u][1].y);
        hi.y = cvtpk(Breg[u][2].y, Breg[u][3].y);
        *(uint2v*)(&sB[bb][(c2 * 2) * BKP_ + kq * 4]) = lo;
        *(uint2v*)(&sB[bb][(c2 * 2 + 1) * BKP_ + kq * 4]) = hi;
      }
    }
  };
  auto compute = [&](int bb) {
    const short* sa = sA[bb];
    const short* sb = sB[bb];
    __builtin_amdgcn_s_setprio(1);
    #pragma unroll
    for (int kk = 0; kk < BK_; kk += 32) {
      s16x8 aF[MREP], bF[NREP];
      #pragma unroll
      for (int m = 0; m < MREP; m++) {
        int row = wr + m * 16 + l16;
        int slot = ((kk >> 3) + lh) ^ (row & CHM);
        aF[m] = *(const s16x8*)(&sa[row * BK_ + slot * 8]);
      }
      #pragma unroll
      for (int n = 0; n < NREP; n++) {
        int col = wc + n * 16 + l16;
        if constexpr (B16) {
          int slot = ((kk >> 3) + lh) ^ (col & CHM);
          bF[n] = *(const s16x8*)(&sb[col * BK_ + slot * 8]);
        } else {
          int kb = kk + lh * 8;
          s16x4 lo = *(const s16x4*)(&sb[col * BKP_ + kb]);
          s16x4 hi = *(const s16x4*)(&sb[col * BKP_ + kb + 4]);
          bF[n] = __builtin_shufflevector(lo, hi, 0, 1, 2, 3, 4, 5, 6, 7);
        }
      }
      #pragma unroll
      for (int m = 0; m < MREP; m++)
        #pragma unroll
        for (int n = 0; n < NREP; n++)
          acc[m][n] = __builtin_amdgcn_mfma_f32_16x16x32_bf16(aF[m], bF[n], acc[m][n], 0, 0, 0);
    }
    __builtin_amdgcn_s_setprio(0);
  };

  // ---- prologue ----
  stage_issue(0, 0);
  stage_write(0);
  asm volatile("s_waitcnt vmcnt(0)" ::: "memory");
  asm volatile("s_waitcnt lgkmcnt(0)" ::: "memory");
  __builtin_amdgcn_s_barrier();

  // ---- main pipeline ----
  int buf = 0;
  for (int tt = 0; tt < NTILES; ++tt) {
    bool has_next = (tt + 1 < NTILES);
    if (has_next) stage_issue(tt + 1, buf ^ 1);
    compute(buf);
    if (MODE == 0 && tt == KT - 1) {
      #pragma unroll
      for (int m = 0; m < MREP; m++)
        #pragma unroll
        for (int n = 0; n < NREP; n++) {
          #pragma unroll
          for (int r = 0; r < 4; r++) {
            float gv = acc[m][n][r];
            sgate[m][n][r] = f2bf(gv / (1.0f + __expf(-gv)));
          }
          acc[m][n] = zero4;
        }
    }
    if (has_next) {
      stage_write(buf ^ 1);
      asm volatile("s_waitcnt vmcnt(0)" ::: "memory");
      asm volatile("s_waitcnt lgkmcnt(0)" ::: "memory");
      __builtin_amdgcn_s_barrier();
      buf ^= 1;
    }
  }

  // ---- epilogue ----
  #pragma unroll
  for (int m = 0; m < MREP; m++) {
    #pragma unroll
    for (int r = 0; r < 4; r++) {
      int lr = wr + m * 16 + lh * 4 + r;
      if (lr >= rows) continue;
      size_t grow = (MODE == 2) ? (size_t)perm[row0 + lr] : (size_t)(row0 + lr);
      size_t base = grow * (size_t)ldc + n0;
      #pragma unroll
      for (int n = 0; n < NREP; n++) {
        int col = wc + n * 16 + l16;
        float v = acc[m][n][r];
        if constexpr (MODE == 0) {
          ((short*)Cv)[base + col] = f2bf(bf2f(sgate[m][n][r]) * v);
        } else if constexpr (MODE == 1) {
          ((float*)Cv)[base + col] = v;
        } else if constexpr (MODE == 2) {
          ((float*)Cv)[base + col] += v;
        } else if constexpr (MODE == 3) {
          ((short*)Cv)[base + col] = f2bf(v);
        } else {
          float gv = bf2f(graw[base + col]);
          ((short*)Cv)[base + col] = f2bf((gv / (1.0f + __expf(-gv))) * v);
        }
      }
    }
  }
}

// ---------------- launch ----------------
extern "C" void kernel_launch(void* const* d_in, const int* in_sizes, int n_in,
                              void* d_out, int out_size, void* d_ws, size_t ws_size,
                              hipStream_t stream)
{
  const float* h   = (const float*)d_in[0];
  const float* rw  = (const float*)d_in[1];
  const float* gup = (const float*)d_in[2];
  const float* dwn = (const float*)d_in[3];
  const float* sg  = (const float*)d_in[4];
  const float* su  = (const float*)d_in[5];
  const float* sd  = (const float*)d_in[6];
  float* out0   = (float*)d_out;                       // [T, H]
  float* logits = out0 + (size_t)T_TOK * HDIM;         // [T, E]

  char* ws = (char*)d_ws;
  int*   eid    = (int*)ws;                  // 2048 ints
  float* score  = (float*)(ws + 8192);       // 2048 floats
  int*   perm   = (int*)(ws + 16384);        // 2048 ints
  int*   ofs    = (int*)(ws + 24576);        // 9 ints
  short* hb     = (short*)(ws + 32768);                 // [T, H] bf16
  short* xp     = hb  + (size_t)T_TOK * HDIM;           // [T, H] bf16 (perm+scaled)
  short* act_sh = xp  + (size_t)T_TOK * HDIM;           // [T, F] bf16
  short* act_rt = act_sh + (size_t)T_TOK * FDIM;        // [T, F] bf16 (perm space)
  short* sgT    = act_rt + (size_t)T_TOK * FDIM + 8192; // [F, H] bf16 (transposed)
  short* suT    = sgT + (size_t)FDIM * HDIM;            // [F, H] bf16
  short* sdT    = suT + (size_t)FDIM * HDIM;            // [H, F] bf16
  short* graw   = sdT + (size_t)HDIM * FDIM;            // [T, F] bf16 (perm space)

  // weight conversions (shared only)
  tconv_kernel<<<dim3(FDIM/64, HDIM/64), 256, 0, stream>>>(sg, sgT, HDIM, FDIM);
  tconv_kernel<<<dim3(FDIM/64, HDIM/64), 256, 0, stream>>>(su, suT, HDIM, FDIM);
  tconv_kernel<<<dim3(HDIM/64, FDIM/64), 256, 0, stream>>>(sd, sdT, FDIM, HDIM);

  router_kernel<<<T_TOK/4, 256, 0, stream>>>(h, rw, logits, eid, score);
  sort_kernel<<<1, 512, 0, stream>>>(eid, perm, ofs);
  build_kernel<<<T_TOK, 256, 0, stream>>>(h, score, perm, hb, xp);

  const int MT = T_TOK / 128;   // 16

  // shared gate+up fused -> act_sh   (all-bf16, 128x128)
  dim3 g_gu_sh(FDIM / 128, MT);
  moe_gemm<0, true, 128, 128, 64, 2, 2, 2><<<g_gu_sh, 256, 0, stream>>>(
      hb, HDIM, sgT, suT, 0, HDIM, act_sh, FDIM, nullptr, MT, HDIM, nullptr, nullptr);
  // shared down -> out0 (store)      (all-bf16, 128x128)
  dim3 g_dn_sh(HDIM / 128, MT);
  moe_gemm<1, true, 128, 128, 64, 2, 2, 2><<<g_dn_sh, 256, 0, stream>>>(
      act_sh, FDIM, sdT, nullptr, 0, FDIM, out0, HDIM, nullptr, MT, FDIM, nullptr, nullptr);

  // routed gate (grouped, BM=320 read-once) -> graw
  dim3 g_g_rt(FDIM / 64, NEXP * 2);
  moe_gemm<3, false, 320, 64, 32, 4, 1, 3><<<g_g_rt, 256, 0, stream>>>(
      xp, HDIM, gup, nullptr, (long long)HDIM * 2 * FDIM, 2 * FDIM,
      graw, FDIM, ofs, 2, HDIM, nullptr, nullptr);
  // routed up + silu-combine -> act_rt
  moe_gemm<4, false, 320, 64, 32, 4, 1, 3><<<g_g_rt, 256, 0, stream>>>(
      xp, HDIM, gup + FDIM, nullptr, (long long)HDIM * 2 * FDIM, 2 * FDIM,
      act_rt, FDIM, ofs, 2, HDIM, nullptr, graw);
  // routed down (grouped, scatter-accumulate into out0)
  dim3 g_d_rt(HDIM / 64, NEXP * 2);
  moe_gemm<2, false, 320, 64, 32, 4, 1, 3><<<g_d_rt, 256, 0, stream>>>(
      act_rt, FDIM, dwn, nullptr, (long long)FDIM * HDIM, HDIM,
      out0, HDIM, ofs, 2, FDIM, perm, nullptr);
}

// Round 8
// 705.813 us; speedup vs baseline: 1.0043x; 1.0043x over previous
//
#include <hip/hip_runtime.h>

#define T_TOK 2048
#define HDIM  2048
#define FDIM  4096
#define NEXP  8

typedef float f32x4 __attribute__((ext_vector_type(4)));
typedef float fvec4 __attribute__((ext_vector_type(4)));
typedef float fvec2 __attribute__((ext_vector_type(2)));
typedef short s16x4 __attribute__((ext_vector_type(4)));
typedef short s16x8 __attribute__((ext_vector_type(8)));
typedef unsigned uint2v __attribute__((ext_vector_type(2)));

__device__ __forceinline__ short f2bf(float f) {
  union { float f; unsigned u; } c; c.f = f;
  unsigned r = c.u + 0x7FFFu + ((c.u >> 16) & 1u);
  return (short)(r >> 16);
}
__device__ __forceinline__ float bf2f(short h) {
  union { float f; unsigned u; } c; c.u = ((unsigned)(unsigned short)h) << 16;
  return c.f;
}
__device__ __forceinline__ unsigned cvtpk(float lo, float hi) {
  unsigned r;
  asm("v_cvt_pk_bf16_f32 %0, %1, %2" : "=v"(r) : "v"(lo), "v"(hi));
  return r;
}

#define GLL16(gsrc, ldst) \
  __builtin_amdgcn_global_load_lds((const __attribute__((address_space(1))) void*)(gsrc), \
                                   (__attribute__((address_space(3))) void*)(ldst), 16, 0, 0)

// ---------------- merged weight convert+transpose (3 matrices, one launch) ----
__global__ __launch_bounds__(256) void tconv3_kernel(
    const float* __restrict__ sg, const float* __restrict__ su, const float* __restrict__ sd,
    short* __restrict__ sgT, short* __restrict__ suT, short* __restrict__ sdT)
{
  int z = blockIdx.z;
  const float* W; short* WT; int K, N;
  if (z == 0)      { W = sg; WT = sgT; K = HDIM; N = FDIM; }
  else if (z == 1) { W = su; WT = suT; K = HDIM; N = FDIM; }
  else             { W = sd; WT = sdT; K = FDIM; N = HDIM; }
  int n0 = blockIdx.x * 64, k0 = blockIdx.y * 64;
  if (n0 >= N || k0 >= K) return;
  __shared__ float tile[64][65];
  int t = threadIdx.x;
  int tc = t & 15, tr = t >> 4;
  #pragma unroll
  for (int i = 0; i < 4; i++) {
    int k = tr + i * 16;
    fvec4 v = *(const fvec4*)(W + (size_t)(k0 + k) * N + n0 + tc * 4);
    tile[k][tc * 4 + 0] = v.x; tile[k][tc * 4 + 1] = v.y;
    tile[k][tc * 4 + 2] = v.z; tile[k][tc * 4 + 3] = v.w;
  }
  __syncthreads();
  int n = t >> 2, ks = (t & 3) * 16;
  s16x8 o0, o1;
  #pragma unroll
  for (int j = 0; j < 8; j++) {
    o0[j] = f2bf(tile[ks + j][n]);
    o1[j] = f2bf(tile[ks + 8 + j][n]);
  }
  *(s16x8*)(WT + (size_t)(n0 + n) * K + k0 + ks) = o0;
  *(s16x8*)(WT + (size_t)(n0 + n) * K + k0 + ks + 8) = o1;
}

// ---------------- router: logits + top1 + sigmoid score ----------------
__global__ __launch_bounds__(256) void router_kernel(
    const float* __restrict__ h, const float* __restrict__ rw,
    float* __restrict__ logits, int* __restrict__ eid, float* __restrict__ score)
{
  int tok  = blockIdx.x * 4 + (threadIdx.x >> 6);
  int lane = threadIdx.x & 63;
  float a[8] = {0.f,0.f,0.f,0.f,0.f,0.f,0.f,0.f};
  const float* hp = h + (size_t)tok * HDIM;
  for (int i = lane; i < HDIM; i += 64) {
    float hv = hp[i];
    const fvec4* wp = (const fvec4*)(rw + (size_t)i * NEXP);
    fvec4 w0 = wp[0], w1 = wp[1];
    a[0] += hv * w0.x; a[1] += hv * w0.y; a[2] += hv * w0.z; a[3] += hv * w0.w;
    a[4] += hv * w1.x; a[5] += hv * w1.y; a[6] += hv * w1.z; a[7] += hv * w1.w;
  }
  #pragma unroll
  for (int e = 0; e < 8; e++) {
    #pragma unroll
    for (int off = 32; off; off >>= 1)
      a[e] += __shfl_xor(a[e], off, 64);
  }
  if (lane == 0) {
    float best = a[0]; int bi = 0;
    #pragma unroll
    for (int e = 1; e < 8; e++) if (a[e] > best) { best = a[e]; bi = e; }
    #pragma unroll
    for (int e = 0; e < 8; e++) logits[(size_t)tok * NEXP + e] = a[e];
    eid[tok] = bi;
    score[tok] = 1.0f / (1.0f + __expf(-best));
  }
}

// ---------------- stable counting sort of tokens by expert ----------------
__global__ __launch_bounds__(512) void sort_kernel(
    const int* __restrict__ eid, int* __restrict__ perm, int* __restrict__ ofs)
{
  __shared__ int s_cnt[8];
  __shared__ int s_off[9];
  int w = threadIdx.x >> 6, lane = threadIdx.x & 63;
  int cnt = 0;
  for (int b = 0; b < T_TOK; b += 64) {
    int id = eid[b + lane];
    unsigned long long m = __ballot(id == w);
    cnt += __popcll(m);
  }
  if (lane == 0) s_cnt[w] = cnt;
  __syncthreads();
  if (threadIdx.x == 0) {
    int o = 0;
    for (int e = 0; e < 8; e++) { s_off[e] = o; o += s_cnt[e]; }
    s_off[8] = o;
    for (int e = 0; e < 9; e++) ofs[e] = s_off[e];
  }
  __syncthreads();
  int pos = s_off[w];
  for (int b = 0; b < T_TOK; b += 64) {
    int tokidx = b + lane;
    int id = eid[tokidx];
    unsigned long long m = __ballot(id == w);
    if (id == w) {
      int p = pos + __popcll(m & ((1ull << lane) - 1ull));
      perm[p] = tokidx;
    }
    pos += __popcll(m);
  }
}

// ---------------- build bf16 h and permuted+scaled x ----------------
__global__ __launch_bounds__(256) void build_kernel(
    const float* __restrict__ h, const float* __restrict__ score,
    const int* __restrict__ perm, short* __restrict__ hb, short* __restrict__ xp)
{
  int row = blockIdx.x;
  int t = threadIdx.x;
  const fvec4* s1 = (const fvec4*)(h + (size_t)row * HDIM);
  for (int j = t; j < HDIM/4; j += 256) {
    fvec4 v = s1[j];
    s16x4 o = { f2bf(v.x), f2bf(v.y), f2bf(v.z), f2bf(v.w) };
    *(s16x4*)(hb + (size_t)row * HDIM + j*4) = o;
  }
  int tok = perm[row];
  float s = score[tok];
  const fvec4* s2 = (const fvec4*)(h + (size_t)tok * HDIM);
  for (int j = t; j < HDIM/4; j += 256) {
    fvec4 v = s2[j];
    s16x4 o = { f2bf(v.x*s), f2bf(v.y*s), f2bf(v.z*s), f2bf(v.w*s) };
    *(s16x4*)(xp + (size_t)row * HDIM + j*4) = o;
  }
}

// ---------------- unified MoE GEMM, 2-phase double-buffered ----------------
// MODE 0: fused gate-up 2-pass (B16 only); epi silu(g)*u -> bf16
// MODE 1: plain fp32 store
// MODE 2: fp32 scatter-accumulate via perm rows
// MODE 3: plain bf16 store (raw gate)
// MODE 4: epi: g=graw[addr]; silu(g)*acc -> bf16 store
// B16=false: B fp32 [K,N] row-major, reg-staged + cvt_pk.
// B16=true : B bf16 [N,K] row-major, global_load_lds staged.
template<int MODE, bool B16, int BM_, int BN_, int BK_, int WM, int WN, int OCC>
__global__ __launch_bounds__(256, OCC) void moe_gemm(
    const short* __restrict__ A, int lda,
    const void* __restrict__ B0v, const void* __restrict__ B1v,
    long long bstride, int ldb,
    void* __restrict__ Cv, int ldc,
    const int* __restrict__ gofs, int mt_per_g, int K,
    const int* __restrict__ perm, const short* __restrict__ graw)
{
  constexpr int MROW = BM_ / WM;
  constexpr int NCOL = BN_ / WN;
  constexpr int MREP = MROW / 16;
  constexpr int NREP = NCOL / 16;
  constexpr int CHM  = BK_ / 8 - 1;      // k-chunk mask
  constexpr int LPR  = BK_ / 8;          // lanes per A row in a gll
  constexpr int RPG  = 512 / BK_;        // rows per gll (1024B)
  constexpr int GPW  = BM_ / RPG / 4;    // A glls per wave
  constexpr int BGW  = B16 ? (BN_ / RPG / 4) : 1;
  constexpr int BKP_ = B16 ? BK_ : (BK_ + 4);
  constexpr int UPT  = B16 ? 1 : (BN_ * BK_ / 8 / 256);

  __shared__ short sA[2][BM_ * BK_];
  __shared__ short sB[2][BN_ * BKP_];

  int g  = blockIdx.y / mt_per_g;
  int mt = blockIdx.y % mt_per_g;
  int r0 = 0, r1 = T_TOK;
  if (gofs) { r0 = gofs[g]; r1 = gofs[g+1]; }
  int row0 = r0 + mt * BM_;
  if (row0 >= r1) return;
  int rows = r1 - row0; if (rows > BM_) rows = BM_;
  int n0 = blockIdx.x * BN_;

  const float* Bg32 = nullptr;
  const short* Bg16 = nullptr; const short* Bu16 = nullptr;
  if constexpr (B16) {
    Bg16 = (const short*)B0v + (size_t)g * (size_t)bstride;
    if (MODE == 0) Bu16 = (const short*)B1v + (size_t)g * (size_t)bstride;
  } else {
    Bg32 = (const float*)B0v + (size_t)g * (size_t)bstride;
  }

  int tid = threadIdx.x;
  int lane = tid & 63, w = tid >> 6;
  int wr = (w / WN) * MROW;
  int wc = (w % WN) * NCOL;
  int l16 = lane & 15, lh = lane >> 4;

  // swizzle: BK=64 -> r&7 (proven); BK=32 -> (r^(r>>2))&3 (avoids 4-way alias at 64B rows)
  auto ASWZ = [](int r) -> int {
    if constexpr (BK_ == 32) return (r ^ (r >> 2)) & 3;
    else return r & CHM;
  };

  int arow_in = lane / LPR;
  int akoff   = (((lane % LPR) ^ ASWZ(arow_in)) << 3);  // swizzled k offset (shorts)
  const short* aBase[GPW];
  #pragma unroll
  for (int i = 0; i < GPW; i++) {
    int row = (w * GPW + i) * RPG + arow_in;
    int growc = row0 + row; if (growc > T_TOK - 1) growc = T_TOK - 1;
    aBase[i] = A + (size_t)growc * lda + akoff;
  }

  const int KT = K / BK_;
  const int NTILES = (MODE == 0) ? 2 * KT : KT;

  f32x4 zero4 = {0.f, 0.f, 0.f, 0.f};
  f32x4 acc[MREP][NREP];
  #pragma unroll
  for (int m = 0; m < MREP; m++)
    #pragma unroll
    for (int n = 0; n < NREP; n++) acc[m][n] = zero4;
  s16x4 sgate[MODE == 0 ? MREP : 1][MODE == 0 ? NREP : 1];
  fvec2 Breg[UPT][4];

  auto stage_issue = [&](int tt, int bb) {
    int k0 = (tt & (KT - 1)) * BK_;
    if constexpr (B16) {
      const short* BTp = (MODE == 0 && tt >= KT) ? Bu16 : Bg16;
      #pragma unroll
      for (int i = 0; i < BGW; i++) {
        int rbase = (w * BGW + i) * RPG;
        const short* src = BTp + (size_t)(n0 + rbase + arow_in) * ldb + k0 + akoff;
        GLL16(src, &sB[bb][rbase * BK_]);
      }
    } else {
      #pragma unroll
      for (int u = 0; u < UPT; u++) {
        int unit = tid + u * 256;
        int c2 = unit % (BN_ / 2);
        int kq = unit / (BN_ / 2);
        const float* bp = Bg32 + (size_t)(k0 + kq * 4) * ldb + n0 + c2 * 2;
        #pragma unroll
        for (int r = 0; r < 4; r++)
          Breg[u][r] = *(const fvec2*)(bp + (size_t)r * ldb);
      }
    }
    #pragma unroll
    for (int i = 0; i < GPW; i++)
      GLL16(aBase[i] + k0, &sA[bb][(w * GPW + i) * RPG * BK_]);
  };
  auto stage_write = [&](int bb) {
    if constexpr (!B16) {
      #pragma unroll
      for (int u = 0; u < UPT; u++) {
        int unit = tid + u * 256;
        int c2 = unit % (BN_ / 2);
        int kq = unit / (BN_ / 2);
        uint2v lo, hi;
        lo.x = cvtpk(Breg[u][0].x, Breg[u][1].x);
        lo.y = cvtpk(Breg[u][2].x, Breg[u][3].x);
        hi.x = cvtpk(Breg[u][0].y, Breg[u][1].y);
        hi.y = cvtpk(Breg[u][2].y, Breg[u][3].y);
        *(uint2v*)(&sB[bb][(c2 * 2) * BKP_ + kq * 4]) = lo;
        *(uint2v*)(&sB[bb][(c2 * 2 + 1) * BKP_ + kq * 4]) = hi;
      }
    }
  };
  auto compute = [&](int bb) {
    const short* sa = sA[bb];
    const short* sb = sB[bb];
    __builtin_amdgcn_s_setprio(1);
    #pragma unroll
    for (int kk = 0; kk < BK_; kk += 32) {
      s16x8 aF[MREP], bF[NREP];
      #pragma unroll
      for (int m = 0; m < MREP; m++) {
        int row = wr + m * 16 + l16;
        int slot = ((kk >> 3) + lh) ^ ASWZ(row);
        aF[m] = *(const s16x8*)(&sa[row * BK_ + slot * 8]);
      }
      #pragma unroll
      for (int n = 0; n < NREP; n++) {
        int col = wc + n * 16 + l16;
        if constexpr (B16) {
          int slot = ((kk >> 3) + lh) ^ ASWZ(col);
          bF[n] = *(const s16x8*)(&sb[col * BK_ + slot * 8]);
        } else {
          int kb = kk + lh * 8;
          s16x4 lo = *(const s16x4*)(&sb[col * BKP_ + kb]);
          s16x4 hi = *(const s16x4*)(&sb[col * BKP_ + kb + 4]);
          bF[n] = __builtin_shufflevector(lo, hi, 0, 1, 2, 3, 4, 5, 6, 7);
        }
      }
      #pragma unroll
      for (int m = 0; m < MREP; m++)
        #pragma unroll
        for (int n = 0; n < NREP; n++)
          acc[m][n] = __builtin_amdgcn_mfma_f32_16x16x32_bf16(aF[m], bF[n], acc[m][n], 0, 0, 0);
    }
    __builtin_amdgcn_s_setprio(0);
  };

  // ---- prologue ----
  stage_issue(0, 0);
  stage_write(0);
  asm volatile("s_waitcnt vmcnt(0)" ::: "memory");
  asm volatile("s_waitcnt lgkmcnt(0)" ::: "memory");
  __builtin_amdgcn_s_barrier();

  // ---- main pipeline ----
  int buf = 0;
  for (int tt = 0; tt < NTILES; ++tt) {
    bool has_next = (tt + 1 < NTILES);
    if (has_next) stage_issue(tt + 1, buf ^ 1);
    compute(buf);
    if (MODE == 0 && tt == KT - 1) {
      #pragma unroll
      for (int m = 0; m < MREP; m++)
        #pragma unroll
        for (int n = 0; n < NREP; n++) {
          #pragma unroll
          for (int r = 0; r < 4; r++) {
            float gv = acc[m][n][r];
            sgate[m][n][r] = f2bf(gv / (1.0f + __expf(-gv)));
          }
          acc[m][n] = zero4;
        }
    }
    if (has_next) {
      stage_write(buf ^ 1);
      asm volatile("s_waitcnt vmcnt(0)" ::: "memory");
      asm volatile("s_waitcnt lgkmcnt(0)" ::: "memory");
      __builtin_amdgcn_s_barrier();
      buf ^= 1;
    }
  }

  // ---- epilogue ----
  #pragma unroll
  for (int m = 0; m < MREP; m++) {
    #pragma unroll
    for (int r = 0; r < 4; r++) {
      int lr = wr + m * 16 + lh * 4 + r;
      if (lr >= rows) continue;
      size_t grow = (MODE == 2) ? (size_t)perm[row0 + lr] : (size_t)(row0 + lr);
      size_t base = grow * (size_t)ldc + n0;
      #pragma unroll
      for (int n = 0; n < NREP; n++) {
        int col = wc + n * 16 + l16;
        float v = acc[m][n][r];
        if constexpr (MODE == 0) {
          ((short*)Cv)[base + col] = f2bf(bf2f(sgate[m][n][r]) * v);
        } else if constexpr (MODE == 1) {
          ((float*)Cv)[base + col] = v;
        } else if constexpr (MODE == 2) {
          ((float*)Cv)[base + col] += v;
        } else if constexpr (MODE == 3) {
          ((short*)Cv)[base + col] = f2bf(v);
        } else {
          float gv = bf2f(graw[base + col]);
          ((short*)Cv)[base + col] = f2bf((gv / (1.0f + __expf(-gv))) * v);
        }
      }
    }
  }
}

// ---------------- launch ----------------
extern "C" void kernel_launch(void* const* d_in, const int* in_sizes, int n_in,
                              void* d_out, int out_size, void* d_ws, size_t ws_size,
                              hipStream_t stream)
{
  const float* h   = (const float*)d_in[0];
  const float* rw  = (const float*)d_in[1];
  const float* gup = (const float*)d_in[2];
  const float* dwn = (const float*)d_in[3];
  const float* sg  = (const float*)d_in[4];
  const float* su  = (const float*)d_in[5];
  const float* sd  = (const float*)d_in[6];
  float* out0   = (float*)d_out;                       // [T, H]
  float* logits = out0 + (size_t)T_TOK * HDIM;         // [T, E]

  char* ws = (char*)d_ws;
  int*   eid    = (int*)ws;                  // 2048 ints
  float* score  = (float*)(ws + 8192);       // 2048 floats
  int*   perm   = (int*)(ws + 16384);        // 2048 ints
  int*   ofs    = (int*)(ws + 24576);        // 9 ints
  short* hb     = (short*)(ws + 32768);                 // [T, H] bf16
  short* xp     = hb  + (size_t)T_TOK * HDIM;           // [T, H] bf16 (perm+scaled)
  short* act_sh = xp  + (size_t)T_TOK * HDIM;           // [T, F] bf16
  short* act_rt = act_sh + (size_t)T_TOK * FDIM;        // [T, F] bf16 (perm space)
  short* sgT    = act_rt + (size_t)T_TOK * FDIM + 8192; // [F, H] bf16 (transposed)
  short* suT    = sgT + (size_t)FDIM * HDIM;            // [F, H] bf16
  short* sdT    = suT + (size_t)FDIM * HDIM;            // [H, F] bf16
  short* graw   = sdT + (size_t)HDIM * FDIM;            // [T, F] bf16 (perm space)

  // shared weight conversions (one launch)
  tconv3_kernel<<<dim3(64, 64, 3), 256, 0, stream>>>(sg, su, sd, sgT, suT, sdT);

  router_kernel<<<T_TOK/4, 256, 0, stream>>>(h, rw, logits, eid, score);
  sort_kernel<<<1, 512, 0, stream>>>(eid, perm, ofs);
  build_kernel<<<T_TOK, 256, 0, stream>>>(h, score, perm, hb, xp);

  const int MT = T_TOK / 128;   // 16

  // shared gate+up fused -> act_sh   (all-bf16, 128x128x64, R6-proven)
  dim3 g_gu_sh(FDIM / 128, MT);
  moe_gemm<0, true, 128, 128, 64, 2, 2, 2><<<g_gu_sh, 256, 0, stream>>>(
      hb, HDIM, sgT, suT, 0, HDIM, act_sh, FDIM, nullptr, MT, HDIM, nullptr, nullptr);
  // shared down -> out0 (store)      (all-bf16, 128x128x64, R6-proven)
  dim3 g_dn_sh(HDIM / 128, MT);
  moe_gemm<1, true, 128, 128, 64, 2, 2, 2><<<g_dn_sh, 256, 0, stream>>>(
      act_sh, FDIM, sdT, nullptr, 0, FDIM, out0, HDIM, nullptr, MT, FDIM, nullptr, nullptr);

  // routed: 128x128x32 wave-tile-64x64 fp32-B path, mt_per_g=4 (512-row cap)
  // gate -> graw
  dim3 g_g_rt(FDIM / 128, NEXP * 4);
  moe_gemm<3, false, 128, 128, 32, 2, 2, 3><<<g_g_rt, 256, 0, stream>>>(
      xp, HDIM, gup, nullptr, (long long)HDIM * 2 * FDIM, 2 * FDIM,
      graw, FDIM, ofs, 4, HDIM, nullptr, nullptr);
  // up + silu-combine -> act_rt
  moe_gemm<4, false, 128, 128, 32, 2, 2, 3><<<g_g_rt, 256, 0, stream>>>(
      xp, HDIM, gup + FDIM, nullptr, (long long)HDIM * 2 * FDIM, 2 * FDIM,
      act_rt, FDIM, ofs, 4, HDIM, nullptr, graw);
  // down (scatter-accumulate into out0)
  dim3 g_d_rt(HDIM / 128, NEXP * 4);
  moe_gemm<2, false, 128, 128, 32, 2, 2, 3><<<g_d_rt, 256, 0, stream>>>(
      act_rt, FDIM, dwn, nullptr, (long long)FDIM * HDIM, HDIM,
      out0, HDIM, ofs, 4, FDIM, perm, nullptr);
}

// Round 9
// 622.488 us; speedup vs baseline: 1.1387x; 1.1339x over previous
//
#include <hip/hip_runtime.h>

#define T_TOK 2048
#define HDIM  2048
#define FDIM  4096
#define NEXP  8

typedef float f32x4 __attribute__((ext_vector_type(4)));
typedef float fvec4 __attribute__((ext_vector_type(4)));
typedef short s16x4 __attribute__((ext_vector_type(4)));
typedef short s16x8 __attribute__((ext_vector_type(8)));
typedef unsigned uint2v __attribute__((ext_vector_type(2)));

__device__ __forceinline__ short f2bf(float f) {
  union { float f; unsigned u; } c; c.f = f;
  unsigned r = c.u + 0x7FFFu + ((c.u >> 16) & 1u);
  return (short)(r >> 16);
}
__device__ __forceinline__ float bf2f(short h) {
  union { float f; unsigned u; } c; c.u = ((unsigned)(unsigned short)h) << 16;
  return c.f;
}
__device__ __forceinline__ unsigned cvtpk(float lo, float hi) {
  unsigned r;
  asm("v_cvt_pk_bf16_f32 %0, %1, %2" : "=v"(r) : "v"(lo), "v"(hi));
  return r;
}

#define GLL16(gsrc, ldst) \
  __builtin_amdgcn_global_load_lds((const __attribute__((address_space(1))) void*)(gsrc), \
                                   (__attribute__((address_space(3))) void*)(ldst), 16, 0, 0)

// ---------------- merged weight convert+transpose (3 matrices, one launch) ----
__global__ __launch_bounds__(256) void tconv3_kernel(
    const float* __restrict__ sg, const float* __restrict__ su, const float* __restrict__ sd,
    short* __restrict__ sgT, short* __restrict__ suT, short* __restrict__ sdT)
{
  int z = blockIdx.z;
  const float* W; short* WT; int K, N;
  if (z == 0)      { W = sg; WT = sgT; K = HDIM; N = FDIM; }
  else if (z == 1) { W = su; WT = suT; K = HDIM; N = FDIM; }
  else             { W = sd; WT = sdT; K = FDIM; N = HDIM; }
  int n0 = blockIdx.x * 64, k0 = blockIdx.y * 64;
  if (n0 >= N || k0 >= K) return;
  __shared__ float tile[64][65];
  int t = threadIdx.x;
  int tc = t & 15, tr = t >> 4;
  #pragma unroll
  for (int i = 0; i < 4; i++) {
    int k = tr + i * 16;
    fvec4 v = *(const fvec4*)(W + (size_t)(k0 + k) * N + n0 + tc * 4);
    tile[k][tc * 4 + 0] = v.x; tile[k][tc * 4 + 1] = v.y;
    tile[k][tc * 4 + 2] = v.z; tile[k][tc * 4 + 3] = v.w;
  }
  __syncthreads();
  int n = t >> 2, ks = (t & 3) * 16;
  s16x8 o0, o1;
  #pragma unroll
  for (int j = 0; j < 8; j++) {
    o0[j] = f2bf(tile[ks + j][n]);
    o1[j] = f2bf(tile[ks + 8 + j][n]);
  }
  *(s16x8*)(WT + (size_t)(n0 + n) * K + k0 + ks) = o0;
  *(s16x8*)(WT + (size_t)(n0 + n) * K + k0 + ks + 8) = o1;
}

// ---------------- router: logits + top1 + sigmoid score ----------------
__global__ __launch_bounds__(256) void router_kernel(
    const float* __restrict__ h, const float* __restrict__ rw,
    float* __restrict__ logits, int* __restrict__ eid, float* __restrict__ score)
{
  int tok  = blockIdx.x * 4 + (threadIdx.x >> 6);
  int lane = threadIdx.x & 63;
  float a[8] = {0.f,0.f,0.f,0.f,0.f,0.f,0.f,0.f};
  const float* hp = h + (size_t)tok * HDIM;
  for (int i = lane; i < HDIM; i += 64) {
    float hv = hp[i];
    const fvec4* wp = (const fvec4*)(rw + (size_t)i * NEXP);
    fvec4 w0 = wp[0], w1 = wp[1];
    a[0] += hv * w0.x; a[1] += hv * w0.y; a[2] += hv * w0.z; a[3] += hv * w0.w;
    a[4] += hv * w1.x; a[5] += hv * w1.y; a[6] += hv * w1.z; a[7] += hv * w1.w;
  }
  #pragma unroll
  for (int e = 0; e < 8; e++) {
    #pragma unroll
    for (int off = 32; off; off >>= 1)
      a[e] += __shfl_xor(a[e], off, 64);
  }
  if (lane == 0) {
    float best = a[0]; int bi = 0;
    #pragma unroll
    for (int e = 1; e < 8; e++) if (a[e] > best) { best = a[e]; bi = e; }
    #pragma unroll
    for (int e = 0; e < 8; e++) logits[(size_t)tok * NEXP + e] = a[e];
    eid[tok] = bi;
    score[tok] = 1.0f / (1.0f + __expf(-best));
  }
}

// ---------------- stable counting sort of tokens by expert ----------------
__global__ __launch_bounds__(512) void sort_kernel(
    const int* __restrict__ eid, int* __restrict__ perm, int* __restrict__ ofs)
{
  __shared__ int s_cnt[8];
  __shared__ int s_off[9];
  int w = threadIdx.x >> 6, lane = threadIdx.x & 63;
  int cnt = 0;
  for (int b = 0; b < T_TOK; b += 64) {
    int id = eid[b + lane];
    unsigned long long m = __ballot(id == w);
    cnt += __popcll(m);
  }
  if (lane == 0) s_cnt[w] = cnt;
  __syncthreads();
  if (threadIdx.x == 0) {
    int o = 0;
    for (int e = 0; e < 8; e++) { s_off[e] = o; o += s_cnt[e]; }
    s_off[8] = o;
    for (int e = 0; e < 9; e++) ofs[e] = s_off[e];
  }
  __syncthreads();
  int pos = s_off[w];
  for (int b = 0; b < T_TOK; b += 64) {
    int tokidx = b + lane;
    int id = eid[tokidx];
    unsigned long long m = __ballot(id == w);
    if (id == w) {
      int p = pos + __popcll(m & ((1ull << lane) - 1ull));
      perm[p] = tokidx;
    }
    pos += __popcll(m);
  }
}

// ---------------- build bf16 h and permuted+scaled x ----------------
__global__ __launch_bounds__(256) void build_kernel(
    const float* __restrict__ h, const float* __restrict__ score,
    const int* __restrict__ perm, short* __restrict__ hb, short* __restrict__ xp)
{
  int row = blockIdx.x;
  int t = threadIdx.x;
  const fvec4* s1 = (const fvec4*)(h + (size_t)row * HDIM);
  for (int j = t; j < HDIM/4; j += 256) {
    fvec4 v = s1[j];
    s16x4 o = { f2bf(v.x), f2bf(v.y), f2bf(v.z), f2bf(v.w) };
    *(s16x4*)(hb + (size_t)row * HDIM + j*4) = o;
  }
  int tok = perm[row];
  float s = score[tok];
  const fvec4* s2 = (const fvec4*)(h + (size_t)tok * HDIM);
  for (int j = t; j < HDIM/4; j += 256) {
    fvec4 v = s2[j];
    s16x4 o = { f2bf(v.x*s), f2bf(v.y*s), f2bf(v.z*s), f2bf(v.w*s) };
    *(s16x4*)(xp + (size_t)row * HDIM + j*4) = o;
  }
}

// ---------------- unified MoE GEMM, 2-phase double-buffered ----------------
// MODE 0: fused gate-up 2-pass (tiles [0,KT)=B0 gate, [KT,2KT)=B1 up); epi silu(g)*u -> bf16
// MODE 1: plain fp32 store
// MODE 2: fp32 accumulate via perm rows
// B16=false: B fp32 [K,N] row-major, reg-staged + cvt_pk.
// B16=true : B bf16 [N,K] row-major, global_load_lds staged.
template<int MODE, bool B16, int BM_, int BN_, int BK_, int WM, int WN, int OCC>
__global__ __launch_bounds__(256, OCC) void moe_gemm(
    const short* __restrict__ A, int lda,
    const void* __restrict__ B0v, const void* __restrict__ B1v,
    long long bstride, int ldb,
    void* __restrict__ Cv, int ldc,
    const int* __restrict__ gofs, int mt_per_g, int K,
    const int* __restrict__ perm)
{
  constexpr int MROW = BM_ / WM;
  constexpr int NCOL = BN_ / WN;
  constexpr int MREP = MROW / 16;
  constexpr int NREP = NCOL / 16;
  constexpr int LPR  = BK_ / 8;          // lanes per A row in a gll
  constexpr int RPG  = 512 / BK_;        // rows per gll (1024B)
  constexpr int GPW  = BM_ / RPG / 4;    // A glls per wave
  constexpr int BGW  = B16 ? (BN_ / RPG / 4) : 1;
  constexpr int BKP_ = B16 ? BK_ : (BK_ + 4);
  constexpr int BUNITS = (BK_ / 4) * (BN_ / 4);  // fp32 B-stage 4x4 quads

  __shared__ short sA[2][BM_ * BK_];
  __shared__ short sB[2][BN_ * BKP_];

  int g  = blockIdx.y / mt_per_g;
  int mt = blockIdx.y % mt_per_g;
  int r0 = 0, r1 = T_TOK;
  if (gofs) { r0 = gofs[g]; r1 = gofs[g+1]; }
  int row0 = r0 + mt * BM_;
  if (row0 >= r1) return;
  int rows = r1 - row0; if (rows > BM_) rows = BM_;
  int n0 = blockIdx.x * BN_;

  const float* Bg32 = nullptr; const float* Bu32 = nullptr;
  const short* Bg16 = nullptr; const short* Bu16 = nullptr;
  if constexpr (B16) {
    Bg16 = (const short*)B0v + (size_t)g * (size_t)bstride;
    if (MODE == 0) Bu16 = (const short*)B1v + (size_t)g * (size_t)bstride;
  } else {
    Bg32 = (const float*)B0v + (size_t)g * (size_t)bstride;
    if (MODE == 0) Bu32 = (const float*)B1v + (size_t)g * (size_t)bstride;
  }

  int tid = threadIdx.x;
  int lane = tid & 63, w = tid >> 6;
  int wr = (w / WN) * MROW;
  int wc = (w % WN) * NCOL;
  int l16 = lane & 15, lh = lane >> 4;

  // swizzle: BK=64 -> r&7 (proven); BK=32 -> (r>>1)&3 (perfect 2-per-128B spread)
  auto ASWZ = [](int r) -> int {
    if constexpr (BK_ == 32) return (r >> 1) & 3;
    else return r & 7;
  };

  int arow_in = lane / LPR;
  int akoff   = (((lane % LPR) ^ ASWZ(arow_in)) << 3);  // pre-swizzled k offset (shorts)
  const short* aBase[GPW];
  #pragma unroll
  for (int i = 0; i < GPW; i++) {
    int row = (w * GPW + i) * RPG + arow_in;
    int growc = row0 + row; if (growc > T_TOK - 1) growc = T_TOK - 1;
    aBase[i] = A + (size_t)growc * lda + akoff;
  }
  // fp32 B-stage mapping: quad grid (BN/4 cols) x (BK/4 rows)
  int bcg  = tid % (BN_ / 4);
  int bkb  = tid / (BN_ / 4);
  bool bact = (tid < BUNITS);

  const int KT = K / BK_;
  const int NTILES = (MODE == 0) ? 2 * KT : KT;

  f32x4 zero4 = {0.f, 0.f, 0.f, 0.f};
  f32x4 acc[MREP][NREP];
  #pragma unroll
  for (int m = 0; m < MREP; m++)
    #pragma unroll
    for (int n = 0; n < NREP; n++) acc[m][n] = zero4;
  s16x4 sgate[MODE == 0 ? MREP : 1][MODE == 0 ? NREP : 1];
  fvec4 Breg[4];

  auto stage_issue = [&](int tt, int bb) {
    int k0 = (tt & (KT - 1)) * BK_;
    if constexpr (B16) {
      const short* BTp = (MODE == 0 && tt >= KT) ? Bu16 : Bg16;
      #pragma unroll
      for (int i = 0; i < BGW; i++) {
        int rbase = (w * BGW + i) * RPG;
        const short* src = BTp + (size_t)(n0 + rbase + arow_in) * ldb + k0 + akoff;
        GLL16(src, &sB[bb][rbase * BK_]);
      }
    } else {
      const float* Bp = (MODE == 0 && tt >= KT) ? Bu32 : Bg32;
      if (bact) {
        const float* bp = Bp + (size_t)(k0 + bkb * 4) * ldb + n0 + bcg * 4;
        #pragma unroll
        for (int r = 0; r < 4; r++)
          Breg[r] = *(const fvec4*)(bp + (size_t)r * ldb);
      }
    }
    #pragma unroll
    for (int i = 0; i < GPW; i++)
      GLL16(aBase[i] + k0, &sA[bb][(w * GPW + i) * RPG * BK_]);
  };
  auto stage_write = [&](int bb) {
    if constexpr (!B16) {
      if (bact) {
        #pragma unroll
        for (int i2 = 0; i2 < 4; i2++) {
          uint2v o;
          o.x = cvtpk(Breg[0][i2], Breg[1][i2]);
          o.y = cvtpk(Breg[2][i2], Breg[3][i2]);
          *(uint2v*)(&sB[bb][(bcg * 4 + i2) * BKP_ + bkb * 4]) = o;
        }
      }
    }
  };
  auto compute = [&](int bb) {
    const short* sa = sA[bb];
    const short* sb = sB[bb];
    __builtin_amdgcn_s_setprio(1);
    #pragma unroll
    for (int kk = 0; kk < BK_; kk += 32) {
      s16x8 aF[MREP], bF[NREP];
      #pragma unroll
      for (int m = 0; m < MREP; m++) {
        int row = wr + m * 16 + l16;
        int slot = ((kk >> 3) + lh) ^ ASWZ(row);
        aF[m] = *(const s16x8*)(&sa[row * BK_ + slot * 8]);
      }
      #pragma unroll
      for (int n = 0; n < NREP; n++) {
        int col = wc + n * 16 + l16;
        if constexpr (B16) {
          int slot = ((kk >> 3) + lh) ^ ASWZ(col);
          bF[n] = *(const s16x8*)(&sb[col * BK_ + slot * 8]);
        } else {
          int kb = kk + lh * 8;
          s16x4 lo = *(const s16x4*)(&sb[col * BKP_ + kb]);
          s16x4 hi = *(const s16x4*)(&sb[col * BKP_ + kb + 4]);
          bF[n] = __builtin_shufflevector(lo, hi, 0, 1, 2, 3, 4, 5, 6, 7);
        }
      }
      #pragma unroll
      for (int m = 0; m < MREP; m++)
        #pragma unroll
        for (int n = 0; n < NREP; n++)
          acc[m][n] = __builtin_amdgcn_mfma_f32_16x16x32_bf16(aF[m], bF[n], acc[m][n], 0, 0, 0);
    }
    __builtin_amdgcn_s_setprio(0);
  };

  // ---- prologue ----
  stage_issue(0, 0);
  stage_write(0);
  asm volatile("s_waitcnt vmcnt(0)" ::: "memory");
  asm volatile("s_waitcnt lgkmcnt(0)" ::: "memory");
  __builtin_amdgcn_s_barrier();

  // ---- main pipeline ----
  int buf = 0;
  for (int tt = 0; tt < NTILES; ++tt) {
    bool has_next = (tt + 1 < NTILES);
    if (has_next) stage_issue(tt + 1, buf ^ 1);
    compute(buf);
    if (MODE == 0 && tt == KT - 1) {
      #pragma unroll
      for (int m = 0; m < MREP; m++)
        #pragma unroll
        for (int n = 0; n < NREP; n++) {
          #pragma unroll
          for (int r = 0; r < 4; r++) {
            float gv = acc[m][n][r];
            sgate[m][n][r] = f2bf(gv / (1.0f + __expf(-gv)));
          }
          acc[m][n] = zero4;
        }
    }
    if (has_next) {
      stage_write(buf ^ 1);
      asm volatile("s_waitcnt vmcnt(0)" ::: "memory");
      asm volatile("s_waitcnt lgkmcnt(0)" ::: "memory");
      __builtin_amdgcn_s_barrier();
      buf ^= 1;
    }
  }

  // ---- epilogue ----
  #pragma unroll
  for (int m = 0; m < MREP; m++) {
    #pragma unroll
    for (int r = 0; r < 4; r++) {
      int lr = wr + m * 16 + lh * 4 + r;
      if (lr >= rows) continue;
      size_t grow = (MODE == 2) ? (size_t)perm[row0 + lr] : (size_t)(row0 + lr);
      size_t base = grow * (size_t)ldc + n0;
      #pragma unroll
      for (int n = 0; n < NREP; n++) {
        int col = wc + n * 16 + l16;
        float v = acc[m][n][r];
        if constexpr (MODE == 0) {
          ((short*)Cv)[base + col] = f2bf(bf2f(sgate[m][n][r]) * v);
        } else if constexpr (MODE == 1) {
          ((float*)Cv)[base + col] = v;
        } else {
          ((float*)Cv)[base + col] += v;
        }
      }
    }
  }
}

// ---------------- launch ----------------
extern "C" void kernel_launch(void* const* d_in, const int* in_sizes, int n_in,
                              void* d_out, int out_size, void* d_ws, size_t ws_size,
                              hipStream_t stream)
{
  const float* h   = (const float*)d_in[0];
  const float* rw  = (const float*)d_in[1];
  const float* gup = (const float*)d_in[2];
  const float* dwn = (const float*)d_in[3];
  const float* sg  = (const float*)d_in[4];
  const float* su  = (const float*)d_in[5];
  const float* sd  = (const float*)d_in[6];
  float* out0   = (float*)d_out;                       // [T, H]
  float* logits = out0 + (size_t)T_TOK * HDIM;         // [T, E]

  char* ws = (char*)d_ws;
  int*   eid    = (int*)ws;                  // 2048 ints
  float* score  = (float*)(ws + 8192);       // 2048 floats
  int*   perm   = (int*)(ws + 16384);        // 2048 ints
  int*   ofs    = (int*)(ws + 24576);        // 9 ints
  short* hb     = (short*)(ws + 32768);                 // [T, H] bf16
  short* xp     = hb  + (size_t)T_TOK * HDIM;           // [T, H] bf16 (perm+scaled)
  short* act_sh = xp  + (size_t)T_TOK * HDIM;           // [T, F] bf16
  short* act_rt = act_sh + (size_t)T_TOK * FDIM;        // [T, F] bf16 (perm space)
  short* sgT    = act_rt + (size_t)T_TOK * FDIM + 8192; // [F, H] bf16 (transposed)
  short* suT    = sgT + (size_t)FDIM * HDIM;            // [F, H] bf16
  short* sdT    = suT + (size_t)FDIM * HDIM;            // [H, F] bf16

  // shared weight conversions (one launch)
  tconv3_kernel<<<dim3(64, 64, 3), 256, 0, stream>>>(sg, su, sd, sgT, suT, sdT);

  router_kernel<<<T_TOK/4, 256, 0, stream>>>(h, rw, logits, eid, score);
  sort_kernel<<<1, 512, 0, stream>>>(eid, perm, ofs);
  build_kernel<<<T_TOK, 256, 0, stream>>>(h, score, perm, hb, xp);

  const int MT = T_TOK / 128;   // 16

  // shared gate+up fused -> act_sh   (all-bf16, 128x128x64, R6-proven)
  dim3 g_gu_sh(FDIM / 128, MT);
  moe_gemm<0, true, 128, 128, 64, 2, 2, 2><<<g_gu_sh, 256, 0, stream>>>(
      hb, HDIM, sgT, suT, 0, HDIM, act_sh, FDIM, nullptr, MT, HDIM, nullptr);
  // shared down -> out0 (store)      (all-bf16, 128x128x64, R6-proven)
  dim3 g_dn_sh(HDIM / 128, MT);
  moe_gemm<1, true, 128, 128, 64, 2, 2, 2><<<g_dn_sh, 256, 0, stream>>>(
      act_sh, FDIM, sdT, nullptr, 0, FDIM, out0, HDIM, nullptr, MT, FDIM, nullptr);

  // routed gate+up fused (grouped) -> act_rt   (fp32-B, 256x64x32, weights read once)
  dim3 g_gu_rt(FDIM / 64, NEXP * 2);
  moe_gemm<0, false, 256, 64, 32, 4, 1, 3><<<g_gu_rt, 256, 0, stream>>>(
      xp, HDIM, gup, gup + FDIM, (long long)HDIM * 2 * FDIM, 2 * FDIM,
      act_rt, FDIM, ofs, 2, HDIM, nullptr);
  // routed down (grouped, accumulate into out0)  (fp32-B, 256x64x32)
  dim3 g_dn_rt(HDIM / 64, NEXP * 2);
  moe_gemm<2, false, 256, 64, 32, 4, 1, 3><<<g_dn_rt, 256, 0, stream>>>(
      act_rt, FDIM, dwn, nullptr, (long long)FDIM * HDIM, HDIM,
      out0, HDIM, ofs, 2, FDIM, perm);
}

// Round 10
// 525.579 us; speedup vs baseline: 1.3487x; 1.1844x over previous
//
#include <hip/hip_runtime.h>

#define T_TOK 2048
#define HDIM  2048
#define FDIM  4096
#define NEXP  8

#define BM 128
#define BK 64
#define NT 256

typedef float f32x4 __attribute__((ext_vector_type(4)));
typedef float fvec4 __attribute__((ext_vector_type(4)));
typedef short s16x4 __attribute__((ext_vector_type(4)));
typedef short s16x8 __attribute__((ext_vector_type(8)));
typedef unsigned uint2v __attribute__((ext_vector_type(2)));

__device__ __forceinline__ short f2bf(float f) {
  union { float f; unsigned u; } c; c.f = f;
  unsigned r = c.u + 0x7FFFu + ((c.u >> 16) & 1u);
  return (short)(r >> 16);
}
__device__ __forceinline__ float bf2f(short h) {
  union { float f; unsigned u; } c; c.u = ((unsigned)(unsigned short)h) << 16;
  return c.f;
}
__device__ __forceinline__ unsigned cvtpk(float lo, float hi) {
  unsigned r;
  asm("v_cvt_pk_bf16_f32 %0, %1, %2" : "=v"(r) : "v"(lo), "v"(hi));
  return r;
}

#define GLL16(gsrc, ldst) \
  __builtin_amdgcn_global_load_lds((const __attribute__((address_space(1))) void*)(gsrc), \
                                   (__attribute__((address_space(3))) void*)(ldst), 16, 0, 0)

// ---------------- merged weight convert+transpose (3 matrices, one launch) ----
__global__ __launch_bounds__(256) void tconv3_kernel(
    const float* __restrict__ sg, const float* __restrict__ su, const float* __restrict__ sd,
    short* __restrict__ sgT, short* __restrict__ suT, short* __restrict__ sdT)
{
  int z = blockIdx.z;
  const float* W; short* WT; int K, N;
  if (z == 0)      { W = sg; WT = sgT; K = HDIM; N = FDIM; }
  else if (z == 1) { W = su; WT = suT; K = HDIM; N = FDIM; }
  else             { W = sd; WT = sdT; K = FDIM; N = HDIM; }
  int n0 = blockIdx.x * 64, k0 = blockIdx.y * 64;
  if (n0 >= N || k0 >= K) return;
  __shared__ float tile[64][65];
  int t = threadIdx.x;
  int tc = t & 15, tr = t >> 4;
  #pragma unroll
  for (int i = 0; i < 4; i++) {
    int k = tr + i * 16;
    fvec4 v = *(const fvec4*)(W + (size_t)(k0 + k) * N + n0 + tc * 4);
    tile[k][tc * 4 + 0] = v.x; tile[k][tc * 4 + 1] = v.y;
    tile[k][tc * 4 + 2] = v.z; tile[k][tc * 4 + 3] = v.w;
  }
  __syncthreads();
  int n = t >> 2, ks = (t & 3) * 16;
  s16x8 o0, o1;
  #pragma unroll
  for (int j = 0; j < 8; j++) {
    o0[j] = f2bf(tile[ks + j][n]);
    o1[j] = f2bf(tile[ks + 8 + j][n]);
  }
  *(s16x8*)(WT + (size_t)(n0 + n) * K + k0 + ks) = o0;
  *(s16x8*)(WT + (size_t)(n0 + n) * K + k0 + ks + 8) = o1;
}

// ---------------- router: logits + top1 + sigmoid score ----------------
__global__ __launch_bounds__(256) void router_kernel(
    const float* __restrict__ h, const float* __restrict__ rw,
    float* __restrict__ logits, int* __restrict__ eid, float* __restrict__ score)
{
  int tok  = blockIdx.x * 4 + (threadIdx.x >> 6);
  int lane = threadIdx.x & 63;
  float a[8] = {0.f,0.f,0.f,0.f,0.f,0.f,0.f,0.f};
  const float* hp = h + (size_t)tok * HDIM;
  for (int i = lane; i < HDIM; i += 64) {
    float hv = hp[i];
    const fvec4* wp = (const fvec4*)(rw + (size_t)i * NEXP);
    fvec4 w0 = wp[0], w1 = wp[1];
    a[0] += hv * w0.x; a[1] += hv * w0.y; a[2] += hv * w0.z; a[3] += hv * w0.w;
    a[4] += hv * w1.x; a[5] += hv * w1.y; a[6] += hv * w1.z; a[7] += hv * w1.w;
  }
  #pragma unroll
  for (int e = 0; e < 8; e++) {
    #pragma unroll
    for (int off = 32; off; off >>= 1)
      a[e] += __shfl_xor(a[e], off, 64);
  }
  if (lane == 0) {
    float best = a[0]; int bi = 0;
    #pragma unroll
    for (int e = 1; e < 8; e++) if (a[e] > best) { best = a[e]; bi = e; }
    #pragma unroll
    for (int e = 0; e < 8; e++) logits[(size_t)tok * NEXP + e] = a[e];
    eid[tok] = bi;
    score[tok] = 1.0f / (1.0f + __expf(-best));
  }
}

// ---------------- stable counting sort of tokens by expert ----------------
__global__ __launch_bounds__(512) void sort_kernel(
    const int* __restrict__ eid, int* __restrict__ perm, int* __restrict__ ofs)
{
  __shared__ int s_cnt[8];
  __shared__ int s_off[9];
  int w = threadIdx.x >> 6, lane = threadIdx.x & 63;
  int cnt = 0;
  for (int b = 0; b < T_TOK; b += 64) {
    int id = eid[b + lane];
    unsigned long long m = __ballot(id == w);
    cnt += __popcll(m);
  }
  if (lane == 0) s_cnt[w] = cnt;
  __syncthreads();
  if (threadIdx.x == 0) {
    int o = 0;
    for (int e = 0; e < 8; e++) { s_off[e] = o; o += s_cnt[e]; }
    s_off[8] = o;
    for (int e = 0; e < 9; e++) ofs[e] = s_off[e];
  }
  __syncthreads();
  int pos = s_off[w];
  for (int b = 0; b < T_TOK; b += 64) {
    int tokidx = b + lane;
    int id = eid[tokidx];
    unsigned long long m = __ballot(id == w);
    if (id == w) {
      int p = pos + __popcll(m & ((1ull << lane) - 1ull));
      perm[p] = tokidx;
    }
    pos += __popcll(m);
  }
}

// ---------------- build bf16 h and permuted+scaled x ----------------
__global__ __launch_bounds__(256) void build_kernel(
    const float* __restrict__ h, const float* __restrict__ score,
    const int* __restrict__ perm, short* __restrict__ hb, short* __restrict__ xp)
{
  int row = blockIdx.x;
  int t = threadIdx.x;
  const fvec4* s1 = (const fvec4*)(h + (size_t)row * HDIM);
  for (int j = t; j < HDIM/4; j += 256) {
    fvec4 v = s1[j];
    s16x4 o = { f2bf(v.x), f2bf(v.y), f2bf(v.z), f2bf(v.w) };
    *(s16x4*)(hb + (size_t)row * HDIM + j*4) = o;
  }
  int tok = perm[row];
  float s = score[tok];
  const fvec4* s2 = (const fvec4*)(h + (size_t)tok * HDIM);
  for (int j = t; j < HDIM/4; j += 256) {
    fvec4 v = s2[j];
    s16x4 o = { f2bf(v.x*s), f2bf(v.y*s), f2bf(v.z*s), f2bf(v.w*s) };
    *(s16x4*)(xp + (size_t)row * HDIM + j*4) = o;
  }
}

// ---------------- unified MoE GEMM ----------------
// MODE 0: fused gate-up 2-pass (tiles [0,KT)=gate, [KT,2KT)=up); epi silu(g)*u -> bf16
// MODE 1: plain fp32 store
// MODE 2: fp32 accumulate via perm rows
// B16=true : B bf16 [N,K], global_load_lds staged, 2-phase dbuf (R6-proven path).
// B16=false: B fp32 [K,N], reg-staged + cvt_pk, DEEP pipeline (distance-2 B loads,
//            counted vmcnt — never drains to 0 in steady state).
template<int MODE, bool B16, int BN_, int OCC>
__global__ __launch_bounds__(NT, OCC) void moe_gemm(
    const short* __restrict__ A, int lda,
    const void* __restrict__ B0v, const void* __restrict__ B1v,
    long long bstride, int ldb,
    void* __restrict__ Cv, int ldc,
    const int* __restrict__ gofs, int mt_per_g, int K,
    const int* __restrict__ perm)
{
  constexpr int NREP = BN_ / 32;          // 16-col frags per wave
  constexpr int CQ   = BN_ / 4;           // fp32-stage col quads
  constexpr int BSTR = B16 ? BK : (BK + 4);

  __shared__ short sA[2][BM * BK];
  __shared__ short sB[2][BN_ * BSTR];

  int g  = blockIdx.y / mt_per_g;
  int mt = blockIdx.y % mt_per_g;
  int r0 = 0, r1 = T_TOK;
  if (gofs) { r0 = gofs[g]; r1 = gofs[g+1]; }
  int row0 = r0 + mt * BM;
  if (row0 >= r1) return;
  int rows = r1 - row0; if (rows > BM) rows = BM;
  int n0 = blockIdx.x * BN_;

  const float* Bg32 = nullptr; const float* Bu32 = nullptr;
  const short* Bg16 = nullptr; const short* Bu16 = nullptr;
  if constexpr (B16) {
    Bg16 = (const short*)B0v + (size_t)g * (size_t)bstride;
    if (MODE == 0) Bu16 = (const short*)B1v + (size_t)g * (size_t)bstride;
  } else {
    Bg32 = (const float*)B0v + (size_t)g * (size_t)bstride;
    if (MODE == 0) Bu32 = (const float*)B1v + (size_t)g * (size_t)bstride;
  }

  int tid = threadIdx.x;
  int lane = tid & 63, w = tid >> 6;
  int wr = (w >> 1) * 64;
  int wc = (w & 1) * (BN_ / 2);
  int l16 = lane & 15, lh = lane >> 4;

  // gll stage lane mapping (shared by A and B16-B)
  int arow_in = lane >> 3;
  int akoff   = (((lane & 7) ^ arow_in) << 3);   // pre-swizzled k offset (shorts)
  const short* aBase[4];
  #pragma unroll
  for (int i = 0; i < 4; i++) {
    int row = (w * 4 + i) * 8 + arow_in;
    int growc = row0 + row; if (growc > T_TOK - 1) growc = T_TOK - 1;
    aBase[i] = A + (size_t)growc * lda + akoff;
  }
  // fp32 B-stage mapping (all 256 threads: 16 col-quads x 16 k-quads)
  int bcg = tid % CQ;
  int bkb = tid / CQ;

  const int KT = K / BK;
  const int NTILES = (MODE == 0) ? 2 * KT : KT;

  f32x4 zero4 = {0.f, 0.f, 0.f, 0.f};
  f32x4 acc[4][NREP];
  #pragma unroll
  for (int m = 0; m < 4; m++)
    #pragma unroll
    for (int n = 0; n < NREP; n++) acc[m][n] = zero4;
  s16x4 sgate[MODE == 0 ? 4 : 1][MODE == 0 ? NREP : 1];

  auto issueA = [&](int tt, int bb) {
    int k0 = (tt & (KT - 1)) * BK;
    #pragma unroll
    for (int i = 0; i < 4; i++)
      GLL16(aBase[i] + k0, &sA[bb][(w * 4 + i) * 8 * BK]);
  };
  auto issueB16 = [&](int tt, int bb) {
    int k0 = (tt & (KT - 1)) * BK;
    const short* BTp = (MODE == 0 && tt >= KT) ? Bu16 : Bg16;
    #pragma unroll
    for (int i = 0; i < BN_ / 32; i++) {
      int rbase = (w * (BN_ / 32) + i) * 8;
      const short* src = BTp + (size_t)(n0 + rbase + arow_in) * ldb + k0 + akoff;
      GLL16(src, &sB[bb][rbase * BSTR]);
    }
  };
  auto issueB32 = [&](int tt, fvec4 (&br)[4]) {
    int k0 = (tt & (KT - 1)) * BK;
    const float* Bp = (MODE == 0 && tt >= KT) ? Bu32 : Bg32;
    const float* bp = Bp + (size_t)(k0 + bkb * 4) * ldb + n0 + bcg * 4;
    #pragma unroll
    for (int r = 0; r < 4; r++)
      br[r] = *(const fvec4*)(bp + (size_t)r * ldb);
  };
  auto writeB32 = [&](fvec4 (&br)[4], int bb) {
    #pragma unroll
    for (int i2 = 0; i2 < 4; i2++) {
      uint2v o;
      o.x = cvtpk(br[0][i2], br[1][i2]);
      o.y = cvtpk(br[2][i2], br[3][i2]);
      *(uint2v*)(&sB[bb][(bcg * 4 + i2) * BSTR + bkb * 4]) = o;
    }
  };
  auto siluGate = [&]() {
    #pragma unroll
    for (int m = 0; m < 4; m++)
      #pragma unroll
      for (int n = 0; n < NREP; n++) {
        #pragma unroll
        for (int r = 0; r < 4; r++) {
          float gv = acc[m][n][r];
          sgate[m][n][r] = f2bf(gv / (1.0f + __expf(-gv)));
        }
        acc[m][n] = zero4;
      }
  };
  auto compute = [&](int bb) {
    const short* sa = sA[bb];
    const short* sb = sB[bb];
    __builtin_amdgcn_s_setprio(1);
    #pragma unroll
    for (int kk = 0; kk < BK; kk += 32) {
      s16x8 aF[4], bF[NREP];
      #pragma unroll
      for (int m = 0; m < 4; m++) {
        int row = wr + m * 16 + l16;
        int slot = ((kk >> 3) + lh) ^ (row & 7);
        aF[m] = *(const s16x8*)(&sa[row * BK + slot * 8]);
      }
      #pragma unroll
      for (int n = 0; n < NREP; n++) {
        int col = wc + n * 16 + l16;
        if constexpr (B16) {
          int slot = ((kk >> 3) + lh) ^ (col & 7);
          bF[n] = *(const s16x8*)(&sb[col * BSTR + slot * 8]);
        } else {
          int kb = kk + lh * 8;
          s16x4 lo = *(const s16x4*)(&sb[col * BSTR + kb]);
          s16x4 hi = *(const s16x4*)(&sb[col * BSTR + kb + 4]);
          bF[n] = __builtin_shufflevector(lo, hi, 0, 1, 2, 3, 4, 5, 6, 7);
        }
      }
      #pragma unroll
      for (int m = 0; m < 4; m++)
        #pragma unroll
        for (int n = 0; n < NREP; n++)
          acc[m][n] = __builtin_amdgcn_mfma_f32_16x16x32_bf16(aF[m], bF[n], acc[m][n], 0, 0, 0);
    }
    __builtin_amdgcn_s_setprio(0);
  };

  if constexpr (B16) {
    // ---- 2-phase dbuf (R6-proven) ----
    issueA(0, 0);
    issueB16(0, 0);
    asm volatile("s_waitcnt vmcnt(0)" ::: "memory");
    asm volatile("s_waitcnt lgkmcnt(0)" ::: "memory");
    __builtin_amdgcn_s_barrier();
    int buf = 0;
    for (int tt = 0; tt < NTILES; ++tt) {
      bool has_next = (tt + 1 < NTILES);
      if (has_next) { issueA(tt + 1, buf ^ 1); issueB16(tt + 1, buf ^ 1); }
      compute(buf);
      if (MODE == 0 && tt == KT - 1) siluGate();
      if (has_next) {
        asm volatile("s_waitcnt vmcnt(0)" ::: "memory");
        asm volatile("s_waitcnt lgkmcnt(0)" ::: "memory");
        __builtin_amdgcn_s_barrier();
        buf ^= 1;
      }
    }
  } else {
    // ---- deep pipeline: distance-2 B loads, counted vmcnt ----
    fvec4 BrA[4], BrB[4];
    // prologue: tile 0 fully staged; B(1) in flight in BrB
    issueA(0, 0);
    issueB32(0, BrA);
    asm volatile("s_waitcnt vmcnt(0)" ::: "memory");
    writeB32(BrA, 0);
    issueB32(1, BrB);
    asm volatile("s_waitcnt lgkmcnt(0)" ::: "memory");
    __builtin_amdgcn_s_barrier();
    int buf = 0;
    // NTILES is even (64) in all !B16 uses; body unrolled 2x for reg ping-pong
    for (int tt = 0; tt < NTILES; tt += 2) {
      // even phase: BrB holds B(tt+1)
      {
        bool hn2 = (tt + 2 < NTILES);
        issueA(tt + 1, buf ^ 1);
        if (hn2) issueB32(tt + 2, BrA);
        compute(buf);
        if (MODE == 0 && tt == KT - 1) siluGate();
        if (hn2) asm volatile("s_waitcnt vmcnt(8)" ::: "memory");
        else     asm volatile("s_waitcnt vmcnt(4)" ::: "memory");
        writeB32(BrB, buf ^ 1);
        if (hn2) asm volatile("s_waitcnt vmcnt(4)" ::: "memory");
        else     asm volatile("s_waitcnt vmcnt(0)" ::: "memory");
        asm volatile("s_waitcnt lgkmcnt(0)" ::: "memory");
        __builtin_amdgcn_s_barrier();
        buf ^= 1;
      }
      // odd phase: BrA holds B(tt+2)
      {
        int t1 = tt + 1;
        bool hn  = (t1 + 1 < NTILES);
        bool hn2 = (t1 + 2 < NTILES);
        if (hn) {
          issueA(t1 + 1, buf ^ 1);
          if (hn2) issueB32(t1 + 2, BrB);
          compute(buf);
          if (MODE == 0 && t1 == KT - 1) siluGate();
          if (hn2) asm volatile("s_waitcnt vmcnt(8)" ::: "memory");
          else     asm volatile("s_waitcnt vmcnt(4)" ::: "memory");
          writeB32(BrA, buf ^ 1);
          if (hn2) asm volatile("s_waitcnt vmcnt(4)" ::: "memory");
          else     asm volatile("s_waitcnt vmcnt(0)" ::: "memory");
          asm volatile("s_waitcnt lgkmcnt(0)" ::: "memory");
          __builtin_amdgcn_s_barrier();
          buf ^= 1;
        } else {
          compute(buf);   // last tile (MODE0's siluGate never lands here: KT-1 < NTILES-1)
        }
      }
    }
  }

  // ---- epilogue ----
  #pragma unroll
  for (int m = 0; m < 4; m++) {
    #pragma unroll
    for (int r = 0; r < 4; r++) {
      int lr = wr + m * 16 + lh * 4 + r;
      if (lr >= rows) continue;
      size_t grow = (MODE == 2) ? (size_t)perm[row0 + lr] : (size_t)(row0 + lr);
      size_t base = grow * (size_t)ldc + n0;
      #pragma unroll
      for (int n = 0; n < NREP; n++) {
        int col = wc + n * 16 + l16;
        float v = acc[m][n][r];
        if constexpr (MODE == 0) {
          ((short*)Cv)[base + col] = f2bf(bf2f(sgate[m][n][r]) * v);
        } else if constexpr (MODE == 1) {
          ((float*)Cv)[base + col] = v;
        } else {
          ((float*)Cv)[base + col] += v;
        }
      }
    }
  }
}

// ---------------- launch ----------------
extern "C" void kernel_launch(void* const* d_in, const int* in_sizes, int n_in,
                              void* d_out, int out_size, void* d_ws, size_t ws_size,
                              hipStream_t stream)
{
  const float* h   = (const float*)d_in[0];
  const float* rw  = (const float*)d_in[1];
  const float* gup = (const float*)d_in[2];
  const float* dwn = (const float*)d_in[3];
  const float* sg  = (const float*)d_in[4];
  const float* su  = (const float*)d_in[5];
  const float* sd  = (const float*)d_in[6];
  float* out0   = (float*)d_out;                       // [T, H]
  float* logits = out0 + (size_t)T_TOK * HDIM;         // [T, E]

  char* ws = (char*)d_ws;
  int*   eid    = (int*)ws;                  // 2048 ints
  float* score  = (float*)(ws + 8192);       // 2048 floats
  int*   perm   = (int*)(ws + 16384);        // 2048 ints
  int*   ofs    = (int*)(ws + 24576);        // 9 ints
  short* hb     = (short*)(ws + 32768);                 // [T, H] bf16
  short* xp     = hb  + (size_t)T_TOK * HDIM;           // [T, H] bf16 (perm+scaled)
  short* act_sh = xp  + (size_t)T_TOK * HDIM;           // [T, F] bf16
  short* act_rt = act_sh + (size_t)T_TOK * FDIM;        // [T, F] bf16 (perm space)
  short* sgT    = act_rt + (size_t)T_TOK * FDIM + 8192; // [F, H] bf16 (transposed)
  short* suT    = sgT + (size_t)FDIM * HDIM;            // [F, H] bf16
  short* sdT    = suT + (size_t)FDIM * HDIM;            // [H, F] bf16

  // shared weight conversions (one launch)
  tconv3_kernel<<<dim3(64, 64, 3), 256, 0, stream>>>(sg, su, sd, sgT, suT, sdT);

  router_kernel<<<T_TOK/4, 256, 0, stream>>>(h, rw, logits, eid, score);
  sort_kernel<<<1, 512, 0, stream>>>(eid, perm, ofs);
  build_kernel<<<T_TOK, 256, 0, stream>>>(h, score, perm, hb, xp);

  const int MT = T_TOK / 128;   // 16

  // shared gate+up fused -> act_sh   (all-bf16, 128x128x64, R6-proven)
  dim3 g_gu_sh(FDIM / 128, MT);
  moe_gemm<0, true, 128, 2><<<g_gu_sh, 256, 0, stream>>>(
      hb, HDIM, sgT, suT, 0, HDIM, act_sh, FDIM, nullptr, MT, HDIM, nullptr);
  // shared down -> out0 (store)      (all-bf16, 128x128x64, R6-proven)
  dim3 g_dn_sh(HDIM / 128, MT);
  moe_gemm<1, true, 128, 2><<<g_dn_sh, 256, 0, stream>>>(
      act_sh, FDIM, sdT, nullptr, 0, FDIM, out0, HDIM, nullptr, MT, FDIM, nullptr);
  // routed gate+up fused (grouped) -> act_rt   (fp32-B deep pipeline, 128x64x64)
  dim3 g_gu_rt(FDIM / 64, NEXP * MT);
  moe_gemm<0, false, 64, 3><<<g_gu_rt, 256, 0, stream>>>(
      xp, HDIM, gup, gup + FDIM, (long long)HDIM * 2 * FDIM, 2 * FDIM,
      act_rt, FDIM, ofs, MT, HDIM, nullptr);
  // routed down (grouped, accumulate into out0)  (fp32-B deep pipeline)
  dim3 g_dn_rt(HDIM / 64, NEXP * MT);
  moe_gemm<2, false, 64, 3><<<g_dn_rt, 256, 0, stream>>>(
      act_rt, FDIM, dwn, nullptr, (long long)FDIM * HDIM, HDIM,
      out0, HDIM, ofs, MT, FDIM, perm);
}